// Round 5
// baseline (239.090 us; speedup 1.0000x reference)
//
#include <hip/hip_runtime.h>
#include <math.h>
#include <stdint.h>

// ---- static problem sizes ----
#define S_    32        // sentences
#define BV_   16        // videos
#define M_    128       // moments
#define C_    256       // channels
#define NN    4096      // N*N
#define P_    2080      // triu(64) count
#define BP    33280     // BV_*P_
#define NSAMP 512       // neg samples per sentence
#define CHUNK 130       // BP / 256

// ---------------- Threefry-2x32 (exact JAX replication, key=(0,42)) -------------
__device__ __forceinline__ uint32_t rotl32(uint32_t x, int n){ return (x<<n) | (x>>(32-n)); }

__device__ __forceinline__ void threefry2x32(uint32_t k0, uint32_t k1, uint32_t &x0, uint32_t &x1){
  uint32_t ks2 = k0 ^ k1 ^ 0x1BD11BDAu;
  x0 += k0; x1 += k1;
  #define TF_R(r) { x0 += x1; x1 = rotl32(x1, r); x1 ^= x0; }
  TF_R(13) TF_R(15) TF_R(26) TF_R(6)
  x0 += k1;  x1 += ks2 + 1u;
  TF_R(17) TF_R(29) TF_R(16) TF_R(24)
  x0 += ks2; x1 += k0 + 2u;
  TF_R(13) TF_R(15) TF_R(26) TF_R(6)
  x0 += k0;  x1 += k1 + 3u;
  TF_R(17) TF_R(29) TF_R(16) TF_R(24)
  x0 += k1;  x1 += ks2 + 4u;
  TF_R(13) TF_R(15) TF_R(26) TF_R(6)
  x0 += ks2; x1 += k0 + 5u;
  #undef TF_R
}

// p in [0,2080) -> triangle (i,j), exact
__device__ __forceinline__ void p_to_ij(int p, int &i, int &j){
  i = (int)((129.0f - sqrtf((float)(16641 - 8*p))) * 0.5f);
  while(64*(i+1) - ((i+1)*i)/2 <= p) ++i;
  while(64*i - (i*(i-1))/2 > p) --i;
  j = i + (p - (64*i - (i*(i-1))/2));
}

// ---------------- top-2 proposals per moment by iou2ds (triu order == flat order)
__global__ __launch_bounds__(256) void k_topk(const float* __restrict__ iou2ds,
                                              int* __restrict__ fpk){
  int m = blockIdx.x;
  const float* row = iou2ds + (size_t)m*NN;
  float v1=-1e30f, v2=-1e30f; int i1=0x7FFFFFFF, i2=0x7FFFFFFF;
  for(int f=threadIdx.x; f<NN; f+=256){
    int ti = f>>6, tj = f&63;
    if(tj < ti) continue;
    float v = row[f];
    if(v > v1 || (v == v1 && f < i1)){ v2=v1; i2=i1; v1=v; i1=f; }
    else if(v > v2 || (v == v2 && f < i2)){ v2=v; i2=f; }
  }
  __shared__ float sv1[256], sv2[256];
  __shared__ int   si1[256], si2[256];
  sv1[threadIdx.x]=v1; sv2[threadIdx.x]=v2; si1[threadIdx.x]=i1; si2[threadIdx.x]=i2;
  for(int stp=128; stp>0; stp>>=1){
    __syncthreads();
    if((int)threadIdx.x < stp){
      float a1=sv1[threadIdx.x], a2=sv2[threadIdx.x];
      int   x1=si1[threadIdx.x], x2=si2[threadIdx.x];
      float b1=sv1[threadIdx.x+stp], b2=sv2[threadIdx.x+stp];
      int   y1=si1[threadIdx.x+stp], y2=si2[threadIdx.x+stp];
      float m1v, m2v; int m1i, m2i;
      bool aTop = (a1 > b1) || (a1 == b1 && x1 < y1);
      if(aTop){
        m1v=a1; m1i=x1;
        if((a2 > b1) || (a2 == b1 && x2 < y1)){ m2v=a2; m2i=x2; } else { m2v=b1; m2i=y1; }
      } else {
        m1v=b1; m1i=y1;
        if((b2 > a1) || (b2 == a1 && y2 < x1)){ m2v=b2; m2i=y2; } else { m2v=a1; m2i=x1; }
      }
      sv1[threadIdx.x]=m1v; sv2[threadIdx.x]=m2v; si1[threadIdx.x]=m1i; si2[threadIdx.x]=m2i;
    }
  }
  __syncthreads();
  if(threadIdx.x==0){
    fpk[m*2+0] = si1[0];
    fpk[m*2+1] = si2[0];
  }
}

// ---------------- pos_vf (normalized) + qsumT, fused: one block per sentence -----
__global__ __launch_bounds__(256) void k_pos(const float* __restrict__ vfeat,
                                             const int* __restrict__ fpk,
                                             float* __restrict__ pos_vf,
                                             float* __restrict__ qsumT){
  int s = blockIdx.x;            // 32
  int c = threadIdx.x;           // 256
  __shared__ float wsum[4];
  __shared__ float s_inv;
  float qs = 0.f;
  for(int r=0; r<8; ++r){
    int row = s*8 + r;
    int fp = fpk[row];
    float v = vfeat[((size_t)s*C_ + c)*NN + fp];
    float ss = v*v;
    for(int o=32;o>0;o>>=1) ss += __shfl_down(ss, o, 64);
    if((c&63)==0) wsum[c>>6]=ss;
    __syncthreads();
    if(c==0){
      float tot = wsum[0]+wsum[1]+wsum[2]+wsum[3];
      s_inv = 1.0f / fmaxf(sqrtf(tot), 1e-12f);
    }
    __syncthreads();
    float pv = v * s_inv;
    pos_vf[(size_t)row*C_ + c] = pv;
    qs += pv;
  }
  qsumT[c*32 + s] = qs;
}

// ---------------- fused norm + bank fill (one 67MB read) -------------------------
// dynamic LDS: tile[256][65] + ssp[256] + invs[64]
__global__ __launch_bounds__(256) void k_bank(const float* __restrict__ vfeat,
                                              float* __restrict__ bank){
  extern __shared__ char dyn_sm[];
  float* tile = (float*)dyn_sm;                  // [256][65]
  float* ssp  = (float*)dyn_sm + 256*65;         // [256]
  float* invs = (float*)dyn_sm + 256*65 + 256;   // [64]

  int i = blockIdx.x;            // triangle row
  int b = blockIdx.y;            // video
  int t = threadIdx.x;
  int j = t & 63, cq = t >> 6;
  const float* basep = vfeat + (size_t)(2*b)*C_*NN + (size_t)i*64;

  float ssq = 0.f;
  for(int it=0; it<64; ++it){
    int cc = it*4 + cq;
    float v = basep[(size_t)cc*NN + j];
    tile[cc*65 + j] = v;
    ssq += v*v;
  }
  ssp[t] = ssq;
  __syncthreads();
  if(t < 64){
    float tot = ssp[t]+ssp[64+t]+ssp[128+t]+ssp[192+t];
    invs[t] = 1.0f/fmaxf(sqrtf(tot), 1e-12f);
  }
  __syncthreads();

  int start = 64*i - (i*(i-1))/2;
  for(int jj=i; jj<64; ++jj){
    size_t row = (size_t)b*P_ + start + (jj - i);
    bank[row*C_ + t] = tile[t*65 + jj] * invs[jj];
  }
}

// ---------------- fused GEMM + keys ----------------------------------------------
__global__ __launch_bounds__(256) void k_fused_keys(const float* __restrict__ bank,
                                                    const float* __restrict__ qsumT,
                                                    const float* __restrict__ iou2d,
                                                    unsigned int* __restrict__ ukey){
  __shared__ float tile[32*257];       // [cc][j]
  const int t = threadIdx.x;
  const int j = blockIdx.x*256 + t;    // 130*256 = 33280 exactly

  // proposal decode (independent of GEMM; hoisted)
  int bv = j / P_;
  int p  = j - bv*P_;
  int pi, pj; p_to_ij(p, pi, pj);
  int fp = pi*64 + pj;
  float iou0 = iou2d[(size_t)(2*bv)*NN + fp];
  float iou1 = iou2d[(size_t)(2*bv+1)*NN + fp];

  float acc[32];
  #pragma unroll
  for(int s=0;s<32;s++) acc[s]=0.f;

  for(int cb=0; cb<8; ++cb){
    __syncthreads();
    #pragma unroll
    for(int it=0; it<8; ++it){
      int idx = it*256 + t;            // 0..2047 float4 units
      int jj  = idx >> 3;              // 0..255
      int c4  = idx & 7;               // 0..7
      float4 v = ((const float4*)bank)[ (size_t)(blockIdx.x*256 + jj)*64 + cb*8 + c4 ];
      tile[(c4*4+0)*257 + jj]=v.x; tile[(c4*4+1)*257 + jj]=v.y;
      tile[(c4*4+2)*257 + jj]=v.z; tile[(c4*4+3)*257 + jj]=v.w;
    }
    __syncthreads();
    const float* qb = qsumT + cb*32*32;
    #pragma unroll 2
    for(int cc=0; cc<32; ++cc){
      float v = tile[cc*257 + t];
      const float* qc = qb + cc*32;    // uniform -> scalar loads
      #pragma unroll
      for(int s=0;s<32;s++) acc[s] = fmaf(qc[s], v, acc[s]);
    }
  }

  #pragma unroll 1
  for(int s=0;s<32;s++){
    float fz = 0.0625f*acc[s] + 0.5f;
    bool pos = ((s>>1)==bv) && (((s&1)?iou1:iou0) > 0.5f);
    float val = pos ? 0.f : fz*fz;
    float key;
    if(val > 0.f){
      float logw = logf(fmaxf(val, 1e-30f));
      unsigned int f = (unsigned int)(s*BP + j);
      const unsigned int HALF = 532480u;   // (S_*BP)/2
      bool second = f >= HALF;
      uint32_t x0 = second ? (f - HALF) : f;
      uint32_t x1 = second ? f : (f + HALF);
      threefry2x32(0u, 42u, x0, x1);
      uint32_t bits = second ? x1 : x0;
      uint32_t fb = (bits >> 9) | 0x3f800000u;
      float f01 = __uint_as_float(fb) - 1.0f;
      const float mn = 1e-7f, mx = 1.0f - 1e-7f;
      float u = fmaxf(mn, f01*(mx-mn) + mn);
      float g = -logf(-logf(u));
      key = logw + g;
    } else {
      key = -INFINITY;
    }
    unsigned int kb = __float_as_uint(key);
    kb = (kb & 0x80000000u) ? ~kb : (kb | 0x80000000u);
    ukey[(size_t)s*BP + j] = kb;
  }
}

// ---------------- exact top-512: replicated-histogram radix + wave scans ----------
__global__ __launch_bounds__(256) void k_select(const unsigned int* __restrict__ ukey,
                                                int* __restrict__ neglist){
  extern __shared__ char dyn_sm[];         // 33280 words
  unsigned int* hist = (unsigned int*)dyn_sm;   // [256][66] = 16896 words (aliased)
  unsigned int* row  = (unsigned int*)dyn_sm;   // full row for emit phase
  __shared__ int s_wave[8];
  __shared__ unsigned int s_prefix;
  __shared__ int s_cntgt, s_need;

  const int s = blockIdx.x;
  const int t = threadIdx.x;
  const int lane = t & 63, wv = t >> 6;
  const unsigned int* grow = ukey + (size_t)s*BP;
  int* list = neglist + s*NSAMP;

  unsigned int prefix = 0, pmask = 0;
  int need = NSAMP, cnt_gt = 0;

  for(int lev=0; lev<4; ++lev){
    const int shift = 24 - 8*lev;
    for(int k=t; k<256*66; k+=256) hist[k] = 0;
    __syncthreads();
    #pragma unroll 2
    for(int k=0; k<CHUNK; ++k){
      unsigned int u = grow[k*256 + t];
      if((u & pmask) == prefix)
        atomicAdd(&hist[((u >> shift) & 255u)*66 + lane], 1u);
    }
    __syncthreads();
    // reduce 64 columns -> h for bin t
    unsigned int h = 0;
    {
      const unsigned int* hr = hist + t*66;
      #pragma unroll
      for(int c=0;c<64;c++) h += hr[c];
    }
    // inclusive suffix scan over 256 bins: in-wave shuffles + cross-wave fixup
    int v = (int)h;
    #pragma unroll
    for(int off=1; off<64; off<<=1){
      int src = lane + off;
      int o = __shfl(v, (src<64)?src:lane, 64);
      v += (src<64)? o : 0;
    }
    if(lane==0) s_wave[wv] = v;
    __syncthreads();
    int tail = 0;
    for(int w2=wv+1; w2<4; ++w2) tail += s_wave[w2];
    int Sb  = v + tail;
    int Sb1 = Sb - (int)h;
    if(Sb >= need && Sb1 < need){
      s_prefix = prefix | ((unsigned int)t << shift);
      s_cntgt  = cnt_gt + Sb1;
      s_need   = need - Sb1;
    }
    __syncthreads();
    prefix = s_prefix; cnt_gt = s_cntgt; need = s_need;
    pmask |= (0xFFu << shift);
    __syncthreads();
  }

  const unsigned int ustar = prefix;
  const int quota = need;

  // stage full row to LDS (coalesced), then count/emit over contiguous chunks
  #pragma unroll 4
  for(int k=0; k<CHUNK; ++k) row[k*256 + t] = grow[k*256 + t];
  __syncthreads();

  int gtc = 0, eqc = 0;
  const int base = t*CHUNK;
  for(int k=0; k<CHUNK; ++k){
    unsigned int u = row[base + k];
    gtc += (u > ustar);
    eqc += (u == ustar);
  }
  // inclusive prefix scans (ascending thread order) via wave shuffles
  int vg = gtc, ve = eqc;
  #pragma unroll
  for(int off=1; off<64; off<<=1){
    int src = lane - off;
    int og = __shfl(vg, (src>=0)?src:lane, 64);
    int oe = __shfl(ve, (src>=0)?src:lane, 64);
    vg += (src>=0)? og : 0;
    ve += (src>=0)? oe : 0;
  }
  if(lane==63){ s_wave[wv] = vg; s_wave[4+wv] = ve; }
  __syncthreads();
  int gbase = 0, ebase = 0;
  for(int w2=0; w2<wv; ++w2){ gbase += s_wave[w2]; ebase += s_wave[4+w2]; }
  int gi = gbase + vg - gtc;          // exclusive gt prefix
  int ei = ebase + ve - eqc;          // exclusive eq prefix

  for(int k=0; k<CHUNK; ++k){
    int jx = base + k;
    unsigned int u = row[jx];
    if(u > ustar){
      list[gi++] = jx;
    } else if(u == ustar){
      if(ei < quota) list[cnt_gt + ei] = jx;
      ei++;
    }
  }
}

// ---------------- fused neg_sum + per-sentence loss -------------------------------
__global__ __launch_bounds__(512) void k_negloss(const float* __restrict__ bank,
                                                 const float* __restrict__ pos_vf,
                                                 const int* __restrict__ neglist,
                                                 float* __restrict__ partial){
  int s = blockIdx.x;
  int t = threadIdx.x;           // 512
  __shared__ float pv[8][260];
  __shared__ float red[8][8];
  __shared__ float ns_s[8];
  for(int idx=t; idx<8*C_; idx+=512) pv[idx>>8][idx&255] = pos_vf[(size_t)(s*8)*C_ + idx];
  __syncthreads();
  int j = neglist[s*NSAMP + t];
  const float4* bp = (const float4*)(bank + (size_t)j*C_);
  float acc[8] = {0,0,0,0,0,0,0,0};
  for(int c4=0; c4<64; ++c4){
    float4 bv = bp[c4];
    #pragma unroll
    for(int a=0;a<8;a++){
      float4 pvv = *(const float4*)&pv[a][c4*4];
      acc[a] += bv.x*pvv.x + bv.y*pvv.y + bv.z*pvv.z + bv.w*pvv.w;
    }
  }
  float e[8];
  #pragma unroll
  for(int a=0;a<8;a++){
    float v = expf(acc[a]/0.1f);
    for(int o=32;o>0;o>>=1) v += __shfl_down(v, o, 64);
    e[a] = v;
  }
  int wv = t>>6;
  if((t&63)==0){
    #pragma unroll
    for(int a=0;a<8;a++) red[wv][a]=e[a];
  }
  __syncthreads();
  if(t < 8){
    float tot = 0.f;
    for(int w=0; w<8; w++) tot += red[w][t];
    ns_s[t] = tot;
  }
  __syncthreads();
  // loss partial (same math/order as previous k_loss)
  if(t < 64){
    int a = t>>3, b = t&7;
    float dot = 0.f;
    for(int c=0;c<C_;c++) dot += pv[a][c]*pv[b][c];
    float pl = dot/0.1f;
    float term = logf(expf(pl) + ns_s[a]) - pl;
    for(int o=32;o>0;o>>=1) term += __shfl_down(term, o, 64);
    if(t==0) partial[s]=term;
  }
}

__global__ void k_final(const float* __restrict__ partial, float* __restrict__ out){
  int t = threadIdx.x;           // 64
  float v = (t < 32) ? partial[t] : 0.f;
  for(int o=32;o>0;o>>=1) v += __shfl_down(v, o, 64);
  if(t==0){
    float loss = v / 2048.0f;
    out[0] = loss * 1.0f;        // WEIGHT = 1.0
    out[1] = loss;
  }
}

// ======================= host launcher =============================================
extern "C" void kernel_launch(void* const* d_in, const int* in_sizes, int n_in,
                              void* d_out, int out_size, void* d_ws, size_t ws_size,
                              hipStream_t stream) {
  const float* video_feats = (const float*)d_in[0];
  const float* iou2d  = (const float*)d_in[4];
  const float* iou2ds = (const float*)d_in[5];

  // workspace layout (bytes, 256-aligned)
  const size_t o_fpk   = 0;            // 256 i32 (1024)
  const size_t o_pvf   = 1024;         // 256*256 f32 (262144)
  const size_t o_qsT   = 263168;       // 256*32 f32 (32768)
  const size_t o_bank  = 295936;       // 33280*256 f32 (34078720)
  const size_t o_ukey  = 34374656;     // 32*33280 u32 (4259840)
  const size_t o_list  = 38634496;     // 32*512 i32 (65536)
  const size_t o_part  = 38700032;     // 32 f32
  const size_t NEED    = 38700160;
  if (ws_size < NEED) return;

  char* w = (char*)d_ws;
  int*          fpk     = (int*)(w + o_fpk);
  float*        pos_vf  = (float*)(w + o_pvf);
  float*        qsumT   = (float*)(w + o_qsT);
  float*        bank    = (float*)(w + o_bank);
  unsigned int* ukey    = (unsigned int*)(w + o_ukey);
  int*          neglist = (int*)(w + o_list);
  float*        part    = (float*)(w + o_part);
  float*        out     = (float*)d_out;

  static bool attr_set = false;
  if(!attr_set){
    (void)hipFuncSetAttribute((const void*)k_select,
                              hipFuncAttributeMaxDynamicSharedMemorySize,
                              BP * 4);
    (void)hipFuncSetAttribute((const void*)k_bank,
                              hipFuncAttributeMaxDynamicSharedMemorySize,
                              (256*65 + 256 + 64) * 4);
    attr_set = true;
  }

  k_topk<<<128, 256, 0, stream>>>(iou2ds, fpk);
  k_pos<<<32, 256, 0, stream>>>(video_feats, fpk, pos_vf, qsumT);
  k_bank<<<dim3(64,16), 256, (256*65 + 256 + 64) * 4, stream>>>(video_feats, bank);
  k_fused_keys<<<130, 256, 0, stream>>>(bank, qsumT, iou2d, ukey);
  k_select<<<32, 256, BP * 4, stream>>>(ukey, neglist);
  k_negloss<<<32, 512, 0, stream>>>(bank, pos_vf, neglist, part);
  k_final<<<1, 64, 0, stream>>>(part, out);
}

// Round 6
// 155.349 us; speedup vs baseline: 1.5390x; 1.5390x over previous
//
#include <hip/hip_runtime.h>
#include <math.h>
#include <stdint.h>

// ---- static problem sizes ----
#define S_    32        // sentences
#define BV_   16        // videos
#define M_    128       // moments
#define C_    256       // channels
#define NN    4096      // N*N
#define P_    2080      // triu(64) count
#define BP    33280     // BV_*P_
#define NSAMP 512       // neg samples per sentence
#define EQCAP 2048      // tie-buffer capacity (ties ~1 in practice)

// ---------------- Threefry-2x32 (exact JAX replication, key=(0,42)) -------------
__device__ __forceinline__ uint32_t rotl32(uint32_t x, int n){ return (x<<n) | (x>>(32-n)); }

__device__ __forceinline__ void threefry2x32(uint32_t k0, uint32_t k1, uint32_t &x0, uint32_t &x1){
  uint32_t ks2 = k0 ^ k1 ^ 0x1BD11BDAu;
  x0 += k0; x1 += k1;
  #define TF_R(r) { x0 += x1; x1 = rotl32(x1, r); x1 ^= x0; }
  TF_R(13) TF_R(15) TF_R(26) TF_R(6)
  x0 += k1;  x1 += ks2 + 1u;
  TF_R(17) TF_R(29) TF_R(16) TF_R(24)
  x0 += ks2; x1 += k0 + 2u;
  TF_R(13) TF_R(15) TF_R(26) TF_R(6)
  x0 += k0;  x1 += k1 + 3u;
  TF_R(17) TF_R(29) TF_R(16) TF_R(24)
  x0 += k1;  x1 += ks2 + 4u;
  TF_R(13) TF_R(15) TF_R(26) TF_R(6)
  x0 += ks2; x1 += k0 + 5u;
  #undef TF_R
}

// p in [0,2080) -> triangle (i,j), exact
__device__ __forceinline__ void p_to_ij(int p, int &i, int &j){
  i = (int)((129.0f - sqrtf((float)(16641 - 8*p))) * 0.5f);
  while(64*(i+1) - ((i+1)*i)/2 <= p) ++i;
  while(64*i - (i*(i-1))/2 > p) --i;
  j = i + (p - (64*i - (i*(i-1))/2));
}

// ---------------- top-2 proposals per moment by iou2ds (triu order == flat order)
__global__ __launch_bounds__(256) void k_topk(const float* __restrict__ iou2ds,
                                              int* __restrict__ fpk){
  int m = blockIdx.x;
  const float* row = iou2ds + (size_t)m*NN;
  float v1=-1e30f, v2=-1e30f; int i1=0x7FFFFFFF, i2=0x7FFFFFFF;
  for(int f=threadIdx.x; f<NN; f+=256){
    int ti = f>>6, tj = f&63;
    if(tj < ti) continue;
    float v = row[f];
    if(v > v1 || (v == v1 && f < i1)){ v2=v1; i2=i1; v1=v; i1=f; }
    else if(v > v2 || (v == v2 && f < i2)){ v2=v; i2=f; }
  }
  __shared__ float sv1[256], sv2[256];
  __shared__ int   si1[256], si2[256];
  sv1[threadIdx.x]=v1; sv2[threadIdx.x]=v2; si1[threadIdx.x]=i1; si2[threadIdx.x]=i2;
  for(int stp=128; stp>0; stp>>=1){
    __syncthreads();
    if((int)threadIdx.x < stp){
      float a1=sv1[threadIdx.x], a2=sv2[threadIdx.x];
      int   x1=si1[threadIdx.x], x2=si2[threadIdx.x];
      float b1=sv1[threadIdx.x+stp], b2=sv2[threadIdx.x+stp];
      int   y1=si1[threadIdx.x+stp], y2=si2[threadIdx.x+stp];
      float m1v, m2v; int m1i, m2i;
      bool aTop = (a1 > b1) || (a1 == b1 && x1 < y1);
      if(aTop){
        m1v=a1; m1i=x1;
        if((a2 > b1) || (a2 == b1 && x2 < y1)){ m2v=a2; m2i=x2; } else { m2v=b1; m2i=y1; }
      } else {
        m1v=b1; m1i=y1;
        if((b2 > a1) || (b2 == a1 && y2 < x1)){ m2v=b2; m2i=y2; } else { m2v=a1; m2i=x1; }
      }
      sv1[threadIdx.x]=m1v; sv2[threadIdx.x]=m2v; si1[threadIdx.x]=m1i; si2[threadIdx.x]=m2i;
    }
  }
  __syncthreads();
  if(threadIdx.x==0){
    fpk[m*2+0] = si1[0];
    fpk[m*2+1] = si2[0];
  }
}

// ---------------- pos_vf (normalized) + qsumT, fused: one block per sentence -----
__global__ __launch_bounds__(256) void k_pos(const float* __restrict__ vfeat,
                                             const int* __restrict__ fpk,
                                             float* __restrict__ pos_vf,
                                             float* __restrict__ qsumT){
  int s = blockIdx.x;            // 32
  int c = threadIdx.x;           // 256
  __shared__ float wsum[4];
  __shared__ float s_inv;
  float qs = 0.f;
  for(int r=0; r<8; ++r){
    int row = s*8 + r;
    int fp = fpk[row];
    float v = vfeat[((size_t)s*C_ + c)*NN + fp];
    float ss = v*v;
    for(int o=32;o>0;o>>=1) ss += __shfl_down(ss, o, 64);
    if((c&63)==0) wsum[c>>6]=ss;
    __syncthreads();
    if(c==0){
      float tot = wsum[0]+wsum[1]+wsum[2]+wsum[3];
      s_inv = 1.0f / fmaxf(sqrtf(tot), 1e-12f);
    }
    __syncthreads();
    float pv = v * s_inv;
    pos_vf[(size_t)row*C_ + c] = pv;
    qs += pv;
  }
  qsumT[c*32 + s] = qs;
}

// ---------------- fused norm + bank fill (one 67MB read) -------------------------
__global__ __launch_bounds__(256) void k_bank(const float* __restrict__ vfeat,
                                              float* __restrict__ bank){
  extern __shared__ char dyn_sm[];
  float* tile = (float*)dyn_sm;                  // [256][65]
  float* ssp  = (float*)dyn_sm + 256*65;         // [256]
  float* invs = (float*)dyn_sm + 256*65 + 256;   // [64]

  int i = blockIdx.x;            // triangle row
  int b = blockIdx.y;            // video
  int t = threadIdx.x;
  int j = t & 63, cq = t >> 6;
  const float* basep = vfeat + (size_t)(2*b)*C_*NN + (size_t)i*64;

  float ssq = 0.f;
  for(int it=0; it<64; ++it){
    int cc = it*4 + cq;
    float v = basep[(size_t)cc*NN + j];
    tile[cc*65 + j] = v;
    ssq += v*v;
  }
  ssp[t] = ssq;
  __syncthreads();
  if(t < 64){
    float tot = ssp[t]+ssp[64+t]+ssp[128+t]+ssp[192+t];
    invs[t] = 1.0f/fmaxf(sqrtf(tot), 1e-12f);
  }
  __syncthreads();

  int start = 64*i - (i*(i-1))/2;
  for(int jj=i; jj<64; ++jj){
    size_t row = (size_t)b*P_ + start + (jj - i);
    bank[row*C_ + t] = tile[t*65 + jj] * invs[jj];
  }
}

// ---------------- fused GEMM + keys ----------------------------------------------
__global__ __launch_bounds__(256) void k_fused_keys(const float* __restrict__ bank,
                                                    const float* __restrict__ qsumT,
                                                    const float* __restrict__ iou2d,
                                                    unsigned int* __restrict__ ukey){
  __shared__ float tile[32*257];       // [cc][j]
  const int t = threadIdx.x;
  const int j = blockIdx.x*256 + t;    // 130*256 = 33280 exactly

  int bv = j / P_;
  int p  = j - bv*P_;
  int pi, pj; p_to_ij(p, pi, pj);
  int fp = pi*64 + pj;
  float iou0 = iou2d[(size_t)(2*bv)*NN + fp];
  float iou1 = iou2d[(size_t)(2*bv+1)*NN + fp];

  float acc[32];
  #pragma unroll
  for(int s=0;s<32;s++) acc[s]=0.f;

  for(int cb=0; cb<8; ++cb){
    __syncthreads();
    #pragma unroll
    for(int it=0; it<8; ++it){
      int idx = it*256 + t;            // 0..2047 float4 units
      int jj  = idx >> 3;              // 0..255
      int c4  = idx & 7;               // 0..7
      float4 v = ((const float4*)bank)[ (size_t)(blockIdx.x*256 + jj)*64 + cb*8 + c4 ];
      tile[(c4*4+0)*257 + jj]=v.x; tile[(c4*4+1)*257 + jj]=v.y;
      tile[(c4*4+2)*257 + jj]=v.z; tile[(c4*4+3)*257 + jj]=v.w;
    }
    __syncthreads();
    const float* qb = qsumT + cb*32*32;
    #pragma unroll 2
    for(int cc=0; cc<32; ++cc){
      float v = tile[cc*257 + t];
      const float* qc = qb + cc*32;    // uniform -> scalar loads
      #pragma unroll
      for(int s=0;s<32;s++) acc[s] = fmaf(qc[s], v, acc[s]);
    }
  }

  #pragma unroll 1
  for(int s=0;s<32;s++){
    float fz = 0.0625f*acc[s] + 0.5f;
    bool pos = ((s>>1)==bv) && (((s&1)?iou1:iou0) > 0.5f);
    float val = pos ? 0.f : fz*fz;
    float key;
    if(val > 0.f){
      float logw = logf(fmaxf(val, 1e-30f));
      unsigned int f = (unsigned int)(s*BP + j);
      const unsigned int HALF = 532480u;   // (S_*BP)/2
      bool second = f >= HALF;
      uint32_t x0 = second ? (f - HALF) : f;
      uint32_t x1 = second ? f : (f + HALF);
      threefry2x32(0u, 42u, x0, x1);
      uint32_t bits = second ? x1 : x0;
      uint32_t fb = (bits >> 9) | 0x3f800000u;
      float f01 = __uint_as_float(fb) - 1.0f;
      const float mn = 1e-7f, mx = 1.0f - 1e-7f;
      float u = fmaxf(mn, f01*(mx-mn) + mn);
      float g = -logf(-logf(u));
      key = logw + g;
    } else {
      key = -INFINITY;
    }
    unsigned int kb = __float_as_uint(key);
    kb = (kb & 0x80000000u) ? ~kb : (kb | 0x80000000u);
    ukey[(size_t)s*BP + j] = kb;
  }
}

// ---------------- exact top-512 v4: LDS row + replicated hist, 1024 threads -------
// One block per sentence, 16 waves. Level-0 histogram fused with LDS staging
// (single global pass). hist[256][17]: 16 lane-columns -> same-address atomic
// chains <=4/wave; pad 17 spreads banks. Selection set == lax.top_k exactly:
// all keys > ustar, plus the `quota` smallest indices among keys == ustar
// (list order is irrelevant downstream; tie choice is index-rank, deterministic).
__global__ __launch_bounds__(1024) void k_select(const unsigned int* __restrict__ ukey,
                                                 int* __restrict__ neglist){
  extern __shared__ char dyn_sm[];
  unsigned int* row  = (unsigned int*)dyn_sm;        // [BP], identity layout
  unsigned int* hist = (unsigned int*)dyn_sm + BP;   // [256*17]
  int* eqbuf = (int*)hist;                           // aliased after descent
  __shared__ int s_wv[16];
  __shared__ unsigned int s_prefix;
  __shared__ int s_cntgt, s_need, s_eq;

  const int s = blockIdx.x;
  const int t = threadIdx.x;
  const int lane = t & 63;
  const int col  = t & 15;
  const unsigned int* grow = ukey + (size_t)s*BP;
  int* list = neglist + s*NSAMP;

  unsigned int prefix = 0, pmask = 0;
  int need = NSAMP, cnt_gt = 0;

  for(int lev=0; lev<4; ++lev){
    const int shift = 24 - 8*lev;
    for(int k=t; k<256*17; k+=1024) hist[k] = 0;
    __syncthreads();
    if(lev==0){
      // fused stage + level-0 histogram (single global pass)
      for(int k=t; k<BP; k+=1024){
        unsigned int u = grow[k];
        row[k] = u;
        atomicAdd(&hist[(u >> 24)*17 + col], 1u);
      }
    } else {
      for(int k=t; k<BP; k+=1024){
        unsigned int u = row[k];
        if((u & pmask) == prefix)
          atomicAdd(&hist[((u >> shift) & 255u)*17 + col], 1u);
      }
    }
    __syncthreads();
    int v = 0; unsigned int h = 0;
    if(t < 256){
      const unsigned int* hr = hist + t*17;
      #pragma unroll
      for(int c=0;c<16;c++) h += hr[c];
      v = (int)h;
      #pragma unroll
      for(int off=1; off<64; off<<=1){
        int src = lane + off;
        int o = __shfl(v, (src<64)?src:lane, 64);
        v += (src<64)? o : 0;
      }
      if(lane==0) s_wv[t>>6] = v;
    }
    __syncthreads();
    if(t < 256){
      int wv4 = t>>6, tail = 0;
      for(int w2=wv4+1; w2<4; ++w2) tail += s_wv[w2];
      int Sb  = v + tail;
      int Sb1 = Sb - (int)h;
      if(Sb >= need && Sb1 < need){
        s_prefix = prefix | ((unsigned int)t << shift);
        s_cntgt  = cnt_gt + Sb1;
        s_need   = need - Sb1;
      }
    }
    __syncthreads();
    prefix = s_prefix; cnt_gt = s_cntgt; need = s_need;
    pmask |= (0xFFu << shift);
    __syncthreads();
  }

  const unsigned int ustar = prefix;   // exact 512th-largest key
  const int quota = need;              // ties to take (smallest indices)

  if(t==0) s_eq = 0;
  __syncthreads();

  // deterministic gt emit: stripe counts -> wave scan -> cross-wave base
  int gtc = 0;
  for(int k=t; k<BP; k+=1024) gtc += (row[k] > ustar) ? 1 : 0;
  int vg = gtc;
  #pragma unroll
  for(int off=1; off<64; off<<=1){
    int src = lane - off;
    int o = __shfl(vg, (src>=0)?src:lane, 64);
    vg += (src>=0)? o : 0;
  }
  const int wv16 = t>>6;
  if(lane==63) s_wv[wv16] = vg;
  __syncthreads();
  int base2 = 0;
  for(int w2=0; w2<wv16; ++w2) base2 += s_wv[w2];
  int gi = base2 + vg - gtc;
  for(int k=t; k<BP; k+=1024){
    unsigned int u = row[k];
    if(u > ustar){
      list[gi++] = k;
    } else if(u == ustar){
      int e = atomicAdd(&s_eq, 1);
      if(e < EQCAP) eqbuf[e] = k;
    }
  }
  __syncthreads();
  const int eqn = s_eq;
  if(eqn <= EQCAP){
    // rank-by-index placement: deterministic regardless of buffer fill order
    for(int i=t; i<eqn; i+=1024){
      int ii = eqbuf[i];
      int r = 0;
      for(int j2=0; j2<eqn; ++j2) r += (eqbuf[j2] < ii) ? 1 : 0;
      if(r < quota) list[cnt_gt + r] = ii;
    }
  } else {
    // degenerate mass-tie fallback (>2048 exact float ties): serial, correct
    if(t==0){
      int taken = 0;
      for(int idx=0; idx<BP && taken<quota; ++idx)
        if(row[idx]==ustar){ list[cnt_gt + taken] = idx; ++taken; }
    }
  }
}

// ---------------- fused neg_sum + per-sentence loss -------------------------------
__global__ __launch_bounds__(512) void k_negloss(const float* __restrict__ bank,
                                                 const float* __restrict__ pos_vf,
                                                 const int* __restrict__ neglist,
                                                 float* __restrict__ partial){
  int s = blockIdx.x;
  int t = threadIdx.x;           // 512
  __shared__ float pv[8][260];
  __shared__ float red[8][8];
  __shared__ float ns_s[8];
  for(int idx=t; idx<8*C_; idx+=512) pv[idx>>8][idx&255] = pos_vf[(size_t)(s*8)*C_ + idx];
  __syncthreads();
  int j = neglist[s*NSAMP + t];
  const float4* bp = (const float4*)(bank + (size_t)j*C_);
  float acc[8] = {0,0,0,0,0,0,0,0};
  for(int c4=0; c4<64; ++c4){
    float4 bv = bp[c4];
    #pragma unroll
    for(int a=0;a<8;a++){
      float4 pvv = *(const float4*)&pv[a][c4*4];
      acc[a] += bv.x*pvv.x + bv.y*pvv.y + bv.z*pvv.z + bv.w*pvv.w;
    }
  }
  float e[8];
  #pragma unroll
  for(int a=0;a<8;a++){
    float v = expf(acc[a]/0.1f);
    for(int o=32;o>0;o>>=1) v += __shfl_down(v, o, 64);
    e[a] = v;
  }
  int wv = t>>6;
  if((t&63)==0){
    #pragma unroll
    for(int a=0;a<8;a++) red[wv][a]=e[a];
  }
  __syncthreads();
  if(t < 8){
    float tot = 0.f;
    for(int w=0; w<8; w++) tot += red[w][t];
    ns_s[t] = tot;
  }
  __syncthreads();
  if(t < 64){
    int a = t>>3, b = t&7;
    float dot = 0.f;
    for(int c=0;c<C_;c++) dot += pv[a][c]*pv[b][c];
    float pl = dot/0.1f;
    float term = logf(expf(pl) + ns_s[a]) - pl;
    for(int o=32;o>0;o>>=1) term += __shfl_down(term, o, 64);
    if(t==0) partial[s]=term;
  }
}

__global__ void k_final(const float* __restrict__ partial, float* __restrict__ out){
  int t = threadIdx.x;           // 64
  float v = (t < 32) ? partial[t] : 0.f;
  for(int o=32;o>0;o>>=1) v += __shfl_down(v, o, 64);
  if(t==0){
    float loss = v / 2048.0f;
    out[0] = loss * 1.0f;        // WEIGHT = 1.0
    out[1] = loss;
  }
}

// ======================= host launcher =============================================
extern "C" void kernel_launch(void* const* d_in, const int* in_sizes, int n_in,
                              void* d_out, int out_size, void* d_ws, size_t ws_size,
                              hipStream_t stream) {
  const float* video_feats = (const float*)d_in[0];
  const float* iou2d  = (const float*)d_in[4];
  const float* iou2ds = (const float*)d_in[5];

  // workspace layout (bytes, 256-aligned)
  const size_t o_fpk   = 0;            // 256 i32 (1024)
  const size_t o_pvf   = 1024;         // 256*256 f32 (262144)
  const size_t o_qsT   = 263168;       // 256*32 f32 (32768)
  const size_t o_bank  = 295936;       // 33280*256 f32 (34078720)
  const size_t o_ukey  = 34374656;     // 32*33280 u32 (4259840)
  const size_t o_list  = 38634496;     // 32*512 i32 (65536)
  const size_t o_part  = 38700032;     // 32 f32
  const size_t NEED    = 38700160;
  if (ws_size < NEED) return;

  char* w = (char*)d_ws;
  int*          fpk     = (int*)(w + o_fpk);
  float*        pos_vf  = (float*)(w + o_pvf);
  float*        qsumT   = (float*)(w + o_qsT);
  float*        bank    = (float*)(w + o_bank);
  unsigned int* ukey    = (unsigned int*)(w + o_ukey);
  int*          neglist = (int*)(w + o_list);
  float*        part    = (float*)(w + o_part);
  float*        out     = (float*)d_out;

  const int SEL_LDS = (BP + 256*17) * 4;   // 150528 B
  static bool attr_set = false;
  if(!attr_set){
    (void)hipFuncSetAttribute((const void*)k_select,
                              hipFuncAttributeMaxDynamicSharedMemorySize,
                              SEL_LDS);
    (void)hipFuncSetAttribute((const void*)k_bank,
                              hipFuncAttributeMaxDynamicSharedMemorySize,
                              (256*65 + 256 + 64) * 4);
    attr_set = true;
  }

  k_topk<<<128, 256, 0, stream>>>(iou2ds, fpk);
  k_pos<<<32, 256, 0, stream>>>(video_feats, fpk, pos_vf, qsumT);
  k_bank<<<dim3(64,16), 256, (256*65 + 256 + 64) * 4, stream>>>(video_feats, bank);
  k_fused_keys<<<130, 256, 0, stream>>>(bank, qsumT, iou2d, ukey);
  k_select<<<32, 1024, SEL_LDS, stream>>>(ukey, neglist);
  k_negloss<<<32, 512, 0, stream>>>(bank, pos_vf, neglist, part);
  k_final<<<1, 64, 0, stream>>>(part, out);
}